// Round 3
// baseline (2687.034 us; speedup 1.0000x reference)
//
#include <hip/hip_runtime.h>

// ============================================================================
// RetinaNetHead (S2ANet-style rotated head), MI355X gfx950.  R3: fix to_nhwc
// (R1/R2 bug: write loop only covered channels 0..127; 128..255 stayed poison).
// Pipeline per call:
//   1. prep_convw: fp32 conv weights -> fp16, rearranged [kk][oc][ic].
//      prep_wc: cls head weights -> fp16 [64][256] (60 valid rows).
//   2. to_nhwc: feats NCHW fp32 -> NHWC fp16.
//   3. per level: conv3x3(x->t1,reg0), conv3x3(t1->t2,reg1),
//      head24_simple(t2->hbuf, fp32 dot w/ raw fp32 weights),
//      conv3x3(x->t1,cls0), conv3x3(t1->t2,cls1), cls_scores(t2->d_out),
//      decode(hbuf->d_out).
// Conv = implicit GEMM, M=B*H*W, N=256, K=9*256; 128x128 tile, BK=64,
// 4 waves of 64x64 via mfma_f32_16x16x32_f16. fp32 accum; logits/decode fp32.
//
// Workspace layout: needs ~245,137,408 B (see offsets in kernel_launch).
// ============================================================================

typedef __attribute__((ext_vector_type(8))) _Float16 f16x8;
typedef __attribute__((ext_vector_type(4))) float f32x4;

#define SCORES_TOTAL 10475520ull  // 8*87296*15

__device__ __forceinline__ unsigned short f2h(float f) {
  union { _Float16 h; unsigned short u; } x;
  x.h = (_Float16)f;  // v_cvt_f16_f32, RNE
  return x.u;
}

__device__ __forceinline__ float sigmf(float x) {
  return 1.0f / (1.0f + expf(-x));
}

// ---------------------------------------------------------------- weight prep
__global__ __launch_bounds__(256) void prep_convw(
    const float* __restrict__ w0, const float* __restrict__ w1,
    const float* __restrict__ w2, const float* __restrict__ w3,
    unsigned short* __restrict__ wtout) {
  int g = blockIdx.x * 256 + threadIdx.x;  // < 4*589824 = 2359296
  int q = g >> 16;            // 0..35
  int wsel = q / 9;
  int kk = q - wsel * 9;      // ky*3+kx
  int r = g & 65535;
  int oc = r >> 8, ic = r & 255;
  const float* src = (wsel == 0) ? w0 : (wsel == 1) ? w1 : (wsel == 2) ? w2 : w3;
  float v = src[(size_t)(oc * 256 + ic) * 9 + kk];  // OIHW flat
  wtout[(size_t)wsel * 589824 + (size_t)((kk << 8) + oc) * 256 + ic] = f2h(v);
}

__global__ __launch_bounds__(256) void prep_wc(
    const float* __restrict__ clsh, unsigned short* __restrict__ wc) {
  int g = blockIdx.x * 256 + threadIdx.x;  // < 16384
  int row = g >> 8, ic = g & 255;
  float v = (row < 60) ? clsh[row * 256 + ic] : 0.0f;
  wc[g] = f2h(v);
}

// ---------------------------------------------------- NCHW fp32 -> NHWC fp16
__global__ __launch_bounds__(256) void to_nhwc(
    const float* __restrict__ in, unsigned short* __restrict__ out,
    int HW, int logHW) {
  __shared__ unsigned short L[64][258];
  const int t = threadIdx.x;
  const int b = blockIdx.y;
  const int hw0 = blockIdx.x * 64;
#pragma unroll
  for (int it = 0; it < 16; ++it) {
    int c = it * 16 + (t >> 4);
    int j4 = (t & 15) * 4;
    float4 v = *reinterpret_cast<const float4*>(
        in + (size_t)(b * 256 + c) * HW + hw0 + j4);
    L[j4 + 0][c] = f2h(v.x);
    L[j4 + 1][c] = f2h(v.y);
    L[j4 + 2][c] = f2h(v.z);
    L[j4 + 3][c] = f2h(v.w);
  }
  __syncthreads();
  // each thread writes 4 channels (8B) -> 64 lanes * 4 = all 256 channels/row
#pragma unroll
  for (int it = 0; it < 16; ++it) {
    int j = it * 4 + (t >> 6);
    int c4 = (t & 63) * 4;
    unsigned v0 = (unsigned)L[j][c4 + 0] | ((unsigned)L[j][c4 + 1] << 16);
    unsigned v1 = (unsigned)L[j][c4 + 2] | ((unsigned)L[j][c4 + 3] << 16);
    uint2 v = make_uint2(v0, v1);
    *reinterpret_cast<uint2*>(
        out + ((size_t)(b << logHW) + hw0 + j) * 256 + c4) = v;
  }
}

// ----------------------------------------------------------- conv3x3 + ReLU
// NHWC fp16 in/out, C=256. Implicit GEMM: tile M=128 x N=128, BK=64.
__global__ __launch_bounds__(256) void conv3x3_mfma(
    const unsigned short* __restrict__ xin,  // [M][256] NHWC fp16
    const unsigned short* __restrict__ wt,   // [9][256 oc][256 ic] fp16
    const float* __restrict__ bias,          // [256] fp32
    unsigned short* __restrict__ yout,       // [M][256] NHWC fp16
    int logW) {
  const int logHW = 2 * logW;
  const int H = 1 << logW, W = H;
  const int HWm1 = (1 << logHW) - 1, Wm1 = W - 1;
  __shared__ unsigned short Al[128 * 72];  // pad 8: 144B row stride
  __shared__ unsigned short Bl[128 * 72];

  const int t = threadIdx.x;
  const int lane = t & 63;
  const int wv = t >> 6;
  const int wm = wv >> 1, wn = wv & 1;
  const int m0 = blockIdx.x * 128, n0 = blockIdx.y * 128;

  const int srow0 = t >> 3;  // 0..31
  const int ssub = t & 7;    // 16B unit within 128B row
  int bj[4], hj[4], wj[4];
#pragma unroll
  for (int j = 0; j < 4; ++j) {
    int m = m0 + srow0 + 32 * j;
    bj[j] = m >> logHW;
    int hw = m & HWm1;
    hj[j] = hw >> logW;
    wj[j] = hw & Wm1;
  }

  f32x4 acc[4][4];
#pragma unroll
  for (int i = 0; i < 4; ++i)
#pragma unroll
    for (int j = 0; j < 4; ++j) acc[i][j] = (f32x4){0.f, 0.f, 0.f, 0.f};

  const int arow = (wm << 6) + (lane & 15);
  const int brow = (wn << 6) + (lane & 15);
  const int kgrp = (lane >> 4) << 3;

#pragma unroll 1
  for (int kstep = 0; kstep < 36; ++kstep) {
    const int kk = kstep >> 2;
    const int ic0 = (kstep & 3) << 6;
    const int dy = kk / 3 - 1, dx = kk - (kk / 3) * 3 - 1;
    __syncthreads();
    // stage A [128 rows][64 ic]
#pragma unroll
    for (int j = 0; j < 4; ++j) {
      int hp = hj[j] + dy, wp = wj[j] + dx;
      bool valid = ((unsigned)hp < (unsigned)H) && ((unsigned)wp < (unsigned)W);
      uint4 v = make_uint4(0u, 0u, 0u, 0u);
      if (valid) {
        size_t src = (((size_t)(bj[j] << logHW) + (hp << logW) + wp) << 8)
                     + ic0 + (ssub << 3);
        v = *reinterpret_cast<const uint4*>(xin + src);
      }
      *reinterpret_cast<uint4*>(&Al[(srow0 + 32 * j) * 72 + (ssub << 3)]) = v;
    }
    // stage B [128 oc][64 ic]
#pragma unroll
    for (int j = 0; j < 4; ++j) {
      int oc = n0 + srow0 + 32 * j;
      size_t src = ((size_t)((kk << 8) + oc) << 8) + ic0 + (ssub << 3);
      uint4 v = *reinterpret_cast<const uint4*>(wt + src);
      *reinterpret_cast<uint4*>(&Bl[(srow0 + 32 * j) * 72 + (ssub << 3)]) = v;
    }
    __syncthreads();
#pragma unroll
    for (int ks = 0; ks < 64; ks += 32) {
      f16x8 a[4], b[4];
#pragma unroll
      for (int mf = 0; mf < 4; ++mf)
        a[mf] = *reinterpret_cast<const f16x8*>(
            &Al[(arow + (mf << 4)) * 72 + ks + kgrp]);
#pragma unroll
      for (int nf = 0; nf < 4; ++nf)
        b[nf] = *reinterpret_cast<const f16x8*>(
            &Bl[(brow + (nf << 4)) * 72 + ks + kgrp]);
#pragma unroll
      for (int mf = 0; mf < 4; ++mf)
#pragma unroll
        for (int nf = 0; nf < 4; ++nf)
          acc[mf][nf] = __builtin_amdgcn_mfma_f32_16x16x32_f16(
              a[mf], b[nf], acc[mf][nf], 0, 0, 0);
    }
  }

  // epilogue: bias + relu + fp16 store. D: col=lane&15, row=(lane>>4)*4+reg.
  const int mrow0 = m0 + (wm << 6) + ((lane >> 4) << 2);
  const int ocol0 = n0 + (wn << 6) + (lane & 15);
#pragma unroll
  for (int nf = 0; nf < 4; ++nf) {
    int oc = ocol0 + (nf << 4);
    float bi = bias[oc];
#pragma unroll
    for (int mf = 0; mf < 4; ++mf)
#pragma unroll
      for (int r = 0; r < 4; ++r) {
        int m = mrow0 + (mf << 4) + r;
        float v = acc[mf][nf][r] + bi;
        v = fmaxf(v, 0.0f);
        yout[((size_t)m << 8) + oc] = f2h(v);
      }
  }
}

// ------------------- bbox(20)+conf(4) head: simple fp32 dot, raw fp32 weights
__global__ __launch_bounds__(256) void head24_simple(
    const unsigned short* __restrict__ t2,  // [M][256] fp16
    const float* __restrict__ regw,         // [20][256] fp32
    const float* __restrict__ regb,         // [20]
    const float* __restrict__ confw,        // [4][256] fp32
    const float* __restrict__ confb,        // [4]
    float* __restrict__ hbuf, int M) {      // [M][24] fp32
  int idx = blockIdx.x * 256 + threadIdx.x;
  if (idx >= M * 24) return;
  int m = idx / 24, c = idx - m * 24;
  const float* w = (c < 20) ? (regw + c * 256) : (confw + (c - 20) * 256);
  float bi = (c < 20) ? regb[c] : confb[c - 20];
  const _Float16* xr = reinterpret_cast<const _Float16*>(t2) + ((size_t)m << 8);
  float s = 0.0f;
#pragma unroll 4
  for (int k = 0; k < 256; k += 8) {
    f16x8 xv = *reinterpret_cast<const f16x8*>(xr + k);
#pragma unroll
    for (int j = 0; j < 8; ++j) s += (float)xv[j] * w[k + j];
  }
  hbuf[(size_t)m * 24 + c] = s + bi;
}

// ------------------------------------------- cls head + sigmoid*sigmoid out
__global__ __launch_bounds__(256) void cls_scores(
    const unsigned short* __restrict__ t2,  // [M][256] fp16
    const unsigned short* __restrict__ wc,  // [64][256] fp16 (60 valid)
    const float* __restrict__ clsb,
    const float* __restrict__ hbuf,         // [M][24] fp32 (conf at 20..23)
    float* __restrict__ outs,               // d_out scores base
    int logHW, int lvl_off) {
  const int t = threadIdx.x, lane = t & 63, wv = t >> 6;
  const int rowb = blockIdx.x * 256 + wv * 64;
  const int kgrp = (lane >> 4) << 3;
  const int l15 = lane & 15;
  const int HWm1 = (1 << logHW) - 1;
  f32x4 acc[4][4];
#pragma unroll
  for (int i = 0; i < 4; ++i)
#pragma unroll
    for (int j = 0; j < 4; ++j) acc[i][j] = (f32x4){0.f, 0.f, 0.f, 0.f};
#pragma unroll
  for (int k0 = 0; k0 < 256; k0 += 32) {
    f16x8 a[4], b[4];
#pragma unroll
    for (int mf = 0; mf < 4; ++mf)
      a[mf] = *reinterpret_cast<const f16x8*>(
          t2 + (((size_t)(rowb + (mf << 4) + l15)) << 8) + k0 + kgrp);
#pragma unroll
    for (int nf = 0; nf < 4; ++nf)
      b[nf] = *reinterpret_cast<const f16x8*>(
          wc + (size_t)(((nf << 4) + l15) << 8) + k0 + kgrp);
#pragma unroll
    for (int mf = 0; mf < 4; ++mf)
#pragma unroll
      for (int nf = 0; nf < 4; ++nf)
        acc[mf][nf] = __builtin_amdgcn_mfma_f32_16x16x32_f16(
            a[mf], b[nf], acc[mf][nf], 0, 0, 0);
  }
#pragma unroll
  for (int nf = 0; nf < 4; ++nf) {
    int c = (nf << 4) + l15;
    if (c < 60) {
      int ai = c / 15, ci = c - ai * 15;
      float bi = clsb[c];
#pragma unroll
      for (int mf = 0; mf < 4; ++mf)
#pragma unroll
        for (int r = 0; r < 4; ++r) {
          int m = rowb + (mf << 4) + ((lane >> 4) << 2) + r;
          float logit = acc[mf][nf][r] + bi;
          float conf = hbuf[(size_t)m * 24 + 20 + ai];
          float sc = sigmf(logit) * sigmf(conf);
          int b = m >> logHW;
          int hw = m & HWm1;
          int loc = lvl_off + (hw << 2) + ai;
          outs[(size_t)b * 1309440 + (size_t)loc * 15 + ci] = sc;
        }
    }
  }
}

// ------------------------------------------------------------- rbox decode
__global__ __launch_bounds__(256) void decode_k(
    const float* __restrict__ hbuf, float* __restrict__ outb,
    int logHW, int logW, int lvl_off, float stride, int total) {
  int tid = blockIdx.x * 256 + threadIdx.x;
  if (tid >= total) return;
  int m = tid >> 2, a = tid & 3;
  const float ANG[4] = {-0.39269908169872414f, 0.39269908169872414f,
                        1.1780972450961724f, 1.9634954084936207f};
  const float* d = hbuf + (size_t)m * 24 + a * 5;
  float dx = d[0], dy = d[1], dw = d[2], dh = d[3], da = d[4];
  int b = m >> logHW, hw = m & ((1 << logHW) - 1);
  int h = hw >> logW, w = hw & ((1 << logW) - 1);
  float ctr = 0.5f * (stride - 1.0f);
  float rx = w * stride + ctr, ry = h * stride + ctr;
  float rw = stride * 1.6329931618554521f;  // 4/sqrt(6)
  float rh = stride * 9.7979589711327124f;  // 4*sqrt(6)
  const float MR = 13.815510557964274f;     // |log(1e-6)|
  dw = fminf(fmaxf(dw, -MR), MR);
  dh = fminf(fmaxf(dh, -MR), MR);
  float gx = dx * rw + rx;
  float gy = dy * rh + ry;
  float gw = rw * expf(dw);
  float gh = rh * expf(dh);
  float v = da + ANG[a] + 0.7853981633974483f;
  float r = fmodf(v, 3.14159265358979323846f);
  if (r < 0.0f) r += 3.14159265358979323846f;
  float ga = r - 0.7853981633974483f;
  int loc = lvl_off + (hw << 2) + a;
  size_t base = (size_t)b * 436480 + (size_t)loc * 5;
  outb[base + 0] = gx;
  outb[base + 1] = gy;
  outb[base + 2] = gw;
  outb[base + 3] = gh;
  outb[base + 4] = ga;
}

// ============================================================================
extern "C" void kernel_launch(void* const* d_in, const int* in_sizes, int n_in,
                              void* d_out, int out_size, void* d_ws,
                              size_t ws_size, hipStream_t stream) {
  const float* feats[5];
  for (int i = 0; i < 5; ++i) feats[i] = (const float*)d_in[i];
  const float* reg_w0 = (const float*)d_in[5];
  const float* reg_b0 = (const float*)d_in[6];
  const float* reg_w1 = (const float*)d_in[7];
  const float* reg_b1 = (const float*)d_in[8];
  const float* cls_w0 = (const float*)d_in[9];
  const float* cls_b0 = (const float*)d_in[10];
  const float* cls_w1 = (const float*)d_in[11];
  const float* cls_b1 = (const float*)d_in[12];
  const float* reg_head_w = (const float*)d_in[13];
  const float* reg_head_b = (const float*)d_in[14];
  const float* cls_head_w = (const float*)d_in[15];
  const float* cls_head_b = (const float*)d_in[16];
  const float* conf_w = (const float*)d_in[17];
  const float* conf_b = (const float*)d_in[18];

  unsigned short* ws = (unsigned short*)d_ws;
  static const size_t xoff[5] = {0ull, 33554432ull, 41943040ull, 44040192ull,
                                 44564480ull};
  unsigned short* t1 = ws + 44695552ull;
  unsigned short* t2 = ws + 78249984ull;
  unsigned short* wt4 = ws + 111804416ull;
  unsigned short* wc = ws + 114171904ull;
  float* hbuf_all = (float*)((char*)d_ws + 228376576ull);

  prep_convw<<<9216, 256, 0, stream>>>(reg_w0, reg_w1, cls_w0, cls_w1, wt4);
  prep_wc<<<64, 256, 0, stream>>>(cls_head_w, wc);

  static const int logWs[5] = {7, 6, 5, 4, 3};
  static const int lvl_off[5] = {0, 65536, 81920, 86016, 87040};
  static const int m_off[5] = {0, 131072, 163840, 172032, 174080};
  static const float strd[5] = {8.f, 16.f, 32.f, 64.f, 128.f};

  for (int l = 0; l < 5; ++l) {
    int HW = 1 << (2 * logWs[l]);
    to_nhwc<<<dim3(HW / 64, 8), 256, 0, stream>>>(feats[l], ws + xoff[l], HW,
                                                  2 * logWs[l]);
  }

  float* scores = (float*)d_out;
  float* boxes = (float*)d_out + SCORES_TOTAL;

  for (int l = 0; l < 5; ++l) {
    const int logW = logWs[l];
    const int HW = 1 << (2 * logW);
    const int M = 8 * HW;
    float* hb = hbuf_all + (size_t)m_off[l] * 24;
    dim3 cgrid(M / 128, 2);
    conv3x3_mfma<<<cgrid, 256, 0, stream>>>(ws + xoff[l], wt4 + 0ull * 589824,
                                            reg_b0, t1, logW);
    conv3x3_mfma<<<cgrid, 256, 0, stream>>>(t1, wt4 + 1ull * 589824, reg_b1,
                                            t2, logW);
    head24_simple<<<(M * 24 + 255) / 256, 256, 0, stream>>>(
        t2, reg_head_w, reg_head_b, conf_w, conf_b, hb, M);
    conv3x3_mfma<<<cgrid, 256, 0, stream>>>(ws + xoff[l], wt4 + 2ull * 589824,
                                            cls_b0, t1, logW);
    conv3x3_mfma<<<cgrid, 256, 0, stream>>>(t1, wt4 + 3ull * 589824, cls_b1,
                                            t2, logW);
    cls_scores<<<M / 256, 256, 0, stream>>>(t2, wc, cls_head_b, hb, scores,
                                            2 * logW, lvl_off[l]);
    decode_k<<<(M * 4 + 255) / 256, 256, 0, stream>>>(
        hb, boxes, 2 * logW, logW, lvl_off[l], strd[l], M * 4);
  }
}

// Round 4
// 1859.911 us; speedup vs baseline: 1.4447x; 1.4447x over previous
//
#include <hip/hip_runtime.h>

// ============================================================================
// RetinaNetHead (S2ANet-style rotated head), MI355X gfx950.
// R4: conv staging via global_load_lds(16B) w/ zero-page clamp for halo;
//     head24 back to MFMA (R1 pattern, exonerated).
// Conv = implicit GEMM, M=B*H*W, N=256, K=9*256; 128x128 tile, BK=64,
// 4 waves of 64x64 via mfma_f32_16x16x32_f16, m97-style 2-barrier K-loop,
// linear LDS [128][64], A/B staged by global_load_lds dwordx4.
// fp32 accum; logits/decode fp32.
//
// Workspace (ushort units):
//   [0)            feats NHWC fp16 (5 levels)
//   [44,695,552)   t1 fp16 (L0-sized, reused across levels)
//   [78,249,984)   t2 fp16 (L0-sized, reused)
//   [111,804,416)  conv weights fp16 4x[9][256][256]
//   [114,163,712)  wh fp16 [32][256]
//   [114,171,904)  wc fp16 [64][256]
//   [114,188,288)  zp (64 ushorts of zeros; 16B zero page)
//   byte 228,376,704: hbuf fp32 [174592][24]   (total ~245.14 MB)
// ============================================================================

typedef __attribute__((ext_vector_type(8))) _Float16 f16x8;
typedef __attribute__((ext_vector_type(4))) float f32x4;

#define SCORES_TOTAL 10475520ull  // 8*87296*15

__device__ __forceinline__ unsigned short f2h(float f) {
  union { _Float16 h; unsigned short u; } x;
  x.h = (_Float16)f;
  return x.u;
}

__device__ __forceinline__ float sigmf(float x) {
  return 1.0f / (1.0f + expf(-x));
}

__device__ __forceinline__ void gload_lds16(const unsigned short* g,
                                            unsigned short* l) {
  __builtin_amdgcn_global_load_lds(
      (const __attribute__((address_space(1))) unsigned int*)g,
      (__attribute__((address_space(3))) unsigned int*)l, 16, 0, 0);
}

// ---------------------------------------------------------------- weight prep
__global__ __launch_bounds__(256) void prep_convw(
    const float* __restrict__ w0, const float* __restrict__ w1,
    const float* __restrict__ w2, const float* __restrict__ w3,
    unsigned short* __restrict__ wtout) {
  int g = blockIdx.x * 256 + threadIdx.x;  // < 4*589824 = 2359296
  int q = g >> 16;            // 0..35
  int wsel = q / 9;
  int kk = q - wsel * 9;      // ky*3+kx
  int r = g & 65535;
  int oc = r >> 8, ic = r & 255;
  const float* src = (wsel == 0) ? w0 : (wsel == 1) ? w1 : (wsel == 2) ? w2 : w3;
  float v = src[(size_t)(oc * 256 + ic) * 9 + kk];  // OIHW flat
  wtout[(size_t)wsel * 589824 + (size_t)((kk << 8) + oc) * 256 + ic] = f2h(v);
}

// wc [64][256], wh [32][256], zero page
__global__ __launch_bounds__(256) void prep_small(
    const float* __restrict__ clsh, const float* __restrict__ regh,
    const float* __restrict__ confw,
    unsigned short* __restrict__ wc, unsigned short* __restrict__ wh,
    unsigned short* __restrict__ zp) {
  int g = blockIdx.x * 256 + threadIdx.x;
  if (g < 16384) {
    int row = g >> 8, ic = g & 255;
    float v = (row < 60) ? clsh[row * 256 + ic] : 0.0f;
    wc[g] = f2h(v);
  } else if (g < 24576) {
    int gg = g - 16384;
    int row = gg >> 8, ic = gg & 255;
    float v = 0.0f;
    if (row < 20) v = regh[row * 256 + ic];
    else if (row < 24) v = confw[(row - 20) * 256 + ic];
    wh[gg] = f2h(v);
  } else if (g < 24640) {
    zp[g - 24576] = 0;
  }
}

// ---------------------------------------------------- NCHW fp32 -> NHWC fp16
__global__ __launch_bounds__(256) void to_nhwc(
    const float* __restrict__ in, unsigned short* __restrict__ out,
    int HW, int logHW) {
  __shared__ unsigned short L[64][258];
  const int t = threadIdx.x;
  const int b = blockIdx.y;
  const int hw0 = blockIdx.x * 64;
#pragma unroll
  for (int it = 0; it < 16; ++it) {
    int c = it * 16 + (t >> 4);
    int j4 = (t & 15) * 4;
    float4 v = *reinterpret_cast<const float4*>(
        in + (size_t)(b * 256 + c) * HW + hw0 + j4);
    L[j4 + 0][c] = f2h(v.x);
    L[j4 + 1][c] = f2h(v.y);
    L[j4 + 2][c] = f2h(v.z);
    L[j4 + 3][c] = f2h(v.w);
  }
  __syncthreads();
#pragma unroll
  for (int it = 0; it < 16; ++it) {
    int j = it * 4 + (t >> 6);
    int c4 = (t & 63) * 4;
    unsigned v0 = (unsigned)L[j][c4 + 0] | ((unsigned)L[j][c4 + 1] << 16);
    unsigned v1 = (unsigned)L[j][c4 + 2] | ((unsigned)L[j][c4 + 3] << 16);
    uint2 v = make_uint2(v0, v1);
    *reinterpret_cast<uint2*>(
        out + ((size_t)(b << logHW) + hw0 + j) * 256 + c4) = v;
  }
}

// ----------------------------------------------------------- conv3x3 + ReLU
// NHWC fp16 in/out, C=256. 128x128 tile, BK=64, global_load_lds staging.
__global__ __launch_bounds__(256) void conv3x3_mfma(
    const unsigned short* __restrict__ xin,  // [M][256] NHWC fp16
    const unsigned short* __restrict__ wt,   // [9][256 oc][256 ic] fp16
    const float* __restrict__ bias,          // [256] fp32
    const unsigned short* __restrict__ zp,   // 16B zeros
    unsigned short* __restrict__ yout,       // [M][256] NHWC fp16
    int logW) {
  const int logHW = 2 * logW;
  const int H = 1 << logW, W = H;
  __shared__ unsigned short Al[128 * 64];  // linear [row][64ic], 128B rows
  __shared__ unsigned short Bl[128 * 64];

  const int t = threadIdx.x;
  const int lane = t & 63;
  const int wv = t >> 6;
  const int wm = wv >> 1, wn = wv & 1;
  const int m0 = blockIdx.x * 128, n0 = blockIdx.y * 128;

  const int rsl = lane >> 3;  // row within 8-row slot
  const int chk = lane & 7;   // 16B chunk within 128B row

  // per-slot precompute (slot = wv*4+i covers rows slot*8..slot*8+7)
  int hS[4], wS[4];
  const unsigned short* aptr[4];
  const unsigned short* bptr[4];
  unsigned short* aldst[4];
  unsigned short* bldst[4];
#pragma unroll
  for (int i = 0; i < 4; ++i) {
    int slot = (wv << 2) + i;
    int m = m0 + (slot << 3) + rsl;
    int hw = m & ((1 << logHW) - 1);
    hS[i] = hw >> logW;
    wS[i] = hw & (W - 1);
    aptr[i] = xin + ((size_t)m << 8) + (chk << 3);
    bptr[i] = wt + ((size_t)(n0 + (slot << 3) + rsl) << 8) + (chk << 3);
    aldst[i] = Al + (slot << 9);  // slot*512 elems = slot*1024 bytes
    bldst[i] = Bl + (slot << 9);
  }

  f32x4 acc[4][4];
#pragma unroll
  for (int i = 0; i < 4; ++i)
#pragma unroll
    for (int j = 0; j < 4; ++j) acc[i][j] = (f32x4){0.f, 0.f, 0.f, 0.f};

  const int arow = (wm << 6) + (lane & 15);
  const int brow = (wn << 6) + (lane & 15);
  const int kb = ((lane >> 4) << 4);  // byte offset of k-group within row

#pragma unroll 1
  for (int kk = 0; kk < 9; ++kk) {
    const int dy = kk / 3 - 1, dx = kk - (kk / 3) * 3 - 1;
    const int moff = (dy * W + dx) << 8;  // element offset for this tap
    bool va[4];
#pragma unroll
    for (int i = 0; i < 4; ++i)
      va[i] = ((unsigned)(hS[i] + dy) < (unsigned)H) &
              ((unsigned)(wS[i] + dx) < (unsigned)W);
    const size_t bko = (size_t)kk << 16;
#pragma unroll 1
    for (int icq = 0; icq < 4; ++icq) {
      const int ic0 = icq << 6;
      __syncthreads();  // previous compute done before LDS overwrite
#pragma unroll
      for (int i = 0; i < 4; ++i) {
        const unsigned short* g = va[i] ? (aptr[i] + moff + ic0) : zp;
        gload_lds16(g, aldst[i]);
      }
#pragma unroll
      for (int i = 0; i < 4; ++i)
        gload_lds16(bptr[i] + bko + ic0, bldst[i]);
      __syncthreads();  // vmcnt(0) drain + barrier: tiles ready
#pragma unroll
      for (int ks = 0; ks < 2; ++ks) {
        f16x8 a[4], b[4];
#pragma unroll
        for (int mf = 0; mf < 4; ++mf)
          a[mf] = *reinterpret_cast<const f16x8*>(
              (const char*)Al + ((arow + (mf << 4)) << 7) + kb + (ks << 6));
#pragma unroll
        for (int nf = 0; nf < 4; ++nf)
          b[nf] = *reinterpret_cast<const f16x8*>(
              (const char*)Bl + ((brow + (nf << 4)) << 7) + kb + (ks << 6));
#pragma unroll
        for (int mf = 0; mf < 4; ++mf)
#pragma unroll
          for (int nf = 0; nf < 4; ++nf)
            acc[mf][nf] = __builtin_amdgcn_mfma_f32_16x16x32_f16(
                a[mf], b[nf], acc[mf][nf], 0, 0, 0);
      }
    }
  }

  // epilogue: bias + relu + fp16 store. D: col=lane&15, row=(lane>>4)*4+reg.
  const int mrow0 = m0 + (wm << 6) + ((lane >> 4) << 2);
  const int ocol0 = n0 + (wn << 6) + (lane & 15);
#pragma unroll
  for (int nf = 0; nf < 4; ++nf) {
    int oc = ocol0 + (nf << 4);
    float bi = bias[oc];
#pragma unroll
    for (int mf = 0; mf < 4; ++mf)
#pragma unroll
      for (int r = 0; r < 4; ++r) {
        int m = mrow0 + (mf << 4) + r;
        float v = acc[mf][nf][r] + bi;
        v = fmaxf(v, 0.0f);
        yout[((size_t)m << 8) + oc] = f2h(v);
      }
  }
}

// -------------------------------------------- bbox(20)+conf(4) head -> hbuf
__global__ __launch_bounds__(256) void head24_mfma(
    const unsigned short* __restrict__ t2,  // [M][256] fp16
    const unsigned short* __restrict__ wh,  // [32][256] fp16 (24 valid)
    const float* __restrict__ regb, const float* __restrict__ confb,
    float* __restrict__ hbuf) {             // [M][24] fp32
  const int t = threadIdx.x, lane = t & 63, wv = t >> 6;
  const int rowb = blockIdx.x * 256 + wv * 64;
  const int kgrp = (lane >> 4) << 3;
  const int l15 = lane & 15;
  f32x4 acc[4][2];
#pragma unroll
  for (int i = 0; i < 4; ++i)
#pragma unroll
    for (int j = 0; j < 2; ++j) acc[i][j] = (f32x4){0.f, 0.f, 0.f, 0.f};
#pragma unroll
  for (int k0 = 0; k0 < 256; k0 += 32) {
    f16x8 a[4], b[2];
#pragma unroll
    for (int mf = 0; mf < 4; ++mf)
      a[mf] = *reinterpret_cast<const f16x8*>(
          t2 + (((size_t)(rowb + (mf << 4) + l15)) << 8) + k0 + kgrp);
#pragma unroll
    for (int nf = 0; nf < 2; ++nf)
      b[nf] = *reinterpret_cast<const f16x8*>(
          wh + (size_t)(((nf << 4) + l15) << 8) + k0 + kgrp);
#pragma unroll
    for (int mf = 0; mf < 4; ++mf)
#pragma unroll
      for (int nf = 0; nf < 2; ++nf)
        acc[mf][nf] = __builtin_amdgcn_mfma_f32_16x16x32_f16(
            a[mf], b[nf], acc[mf][nf], 0, 0, 0);
  }
#pragma unroll
  for (int nf = 0; nf < 2; ++nf) {
    int c = (nf << 4) + l15;
    if (c < 24) {
      float bi = (c < 20) ? regb[c] : confb[c - 20];
#pragma unroll
      for (int mf = 0; mf < 4; ++mf)
#pragma unroll
        for (int r = 0; r < 4; ++r) {
          int m = rowb + (mf << 4) + ((lane >> 4) << 2) + r;
          hbuf[(size_t)m * 24 + c] = acc[mf][nf][r] + bi;
        }
    }
  }
}

// ------------------------------------------- cls head + sigmoid*sigmoid out
__global__ __launch_bounds__(256) void cls_scores(
    const unsigned short* __restrict__ t2,  // [M][256] fp16
    const unsigned short* __restrict__ wc,  // [64][256] fp16 (60 valid)
    const float* __restrict__ clsb,
    const float* __restrict__ hbuf,         // [M][24] fp32 (conf at 20..23)
    float* __restrict__ outs,               // d_out scores base
    int logHW, int lvl_off) {
  const int t = threadIdx.x, lane = t & 63, wv = t >> 6;
  const int rowb = blockIdx.x * 256 + wv * 64;
  const int kgrp = (lane >> 4) << 3;
  const int l15 = lane & 15;
  const int HWm1 = (1 << logHW) - 1;
  f32x4 acc[4][4];
#pragma unroll
  for (int i = 0; i < 4; ++i)
#pragma unroll
    for (int j = 0; j < 4; ++j) acc[i][j] = (f32x4){0.f, 0.f, 0.f, 0.f};
#pragma unroll
  for (int k0 = 0; k0 < 256; k0 += 32) {
    f16x8 a[4], b[4];
#pragma unroll
    for (int mf = 0; mf < 4; ++mf)
      a[mf] = *reinterpret_cast<const f16x8*>(
          t2 + (((size_t)(rowb + (mf << 4) + l15)) << 8) + k0 + kgrp);
#pragma unroll
    for (int nf = 0; nf < 4; ++nf)
      b[nf] = *reinterpret_cast<const f16x8*>(
          wc + (size_t)(((nf << 4) + l15) << 8) + k0 + kgrp);
#pragma unroll
    for (int mf = 0; mf < 4; ++mf)
#pragma unroll
      for (int nf = 0; nf < 4; ++nf)
        acc[mf][nf] = __builtin_amdgcn_mfma_f32_16x16x32_f16(
            a[mf], b[nf], acc[mf][nf], 0, 0, 0);
  }
#pragma unroll
  for (int nf = 0; nf < 4; ++nf) {
    int c = (nf << 4) + l15;
    if (c < 60) {
      int ai = c / 15, ci = c - ai * 15;
      float bi = clsb[c];
#pragma unroll
      for (int mf = 0; mf < 4; ++mf)
#pragma unroll
        for (int r = 0; r < 4; ++r) {
          int m = rowb + (mf << 4) + ((lane >> 4) << 2) + r;
          float logit = acc[mf][nf][r] + bi;
          float conf = hbuf[(size_t)m * 24 + 20 + ai];
          float sc = sigmf(logit) * sigmf(conf);
          int b = m >> logHW;
          int hw = m & HWm1;
          int loc = lvl_off + (hw << 2) + ai;
          outs[(size_t)b * 1309440 + (size_t)loc * 15 + ci] = sc;
        }
    }
  }
}

// ------------------------------------------------------------- rbox decode
__global__ __launch_bounds__(256) void decode_k(
    const float* __restrict__ hbuf, float* __restrict__ outb,
    int logHW, int logW, int lvl_off, float stride, int total) {
  int tid = blockIdx.x * 256 + threadIdx.x;
  if (tid >= total) return;
  int m = tid >> 2, a = tid & 3;
  const float ANG[4] = {-0.39269908169872414f, 0.39269908169872414f,
                        1.1780972450961724f, 1.9634954084936207f};
  const float* d = hbuf + (size_t)m * 24 + a * 5;
  float dx = d[0], dy = d[1], dw = d[2], dh = d[3], da = d[4];
  int b = m >> logHW, hw = m & ((1 << logHW) - 1);
  int h = hw >> logW, w = hw & ((1 << logW) - 1);
  float ctr = 0.5f * (stride - 1.0f);
  float rx = w * stride + ctr, ry = h * stride + ctr;
  float rw = stride * 1.6329931618554521f;  // 4/sqrt(6)
  float rh = stride * 9.7979589711327124f;  // 4*sqrt(6)
  const float MR = 13.815510557964274f;     // |log(1e-6)|
  dw = fminf(fmaxf(dw, -MR), MR);
  dh = fminf(fmaxf(dh, -MR), MR);
  float gx = dx * rw + rx;
  float gy = dy * rh + ry;
  float gw = rw * expf(dw);
  float gh = rh * expf(dh);
  float v = da + ANG[a] + 0.7853981633974483f;
  float r = fmodf(v, 3.14159265358979323846f);
  if (r < 0.0f) r += 3.14159265358979323846f;
  float ga = r - 0.7853981633974483f;
  int loc = lvl_off + (hw << 2) + a;
  size_t base = (size_t)b * 436480 + (size_t)loc * 5;
  outb[base + 0] = gx;
  outb[base + 1] = gy;
  outb[base + 2] = gw;
  outb[base + 3] = gh;
  outb[base + 4] = ga;
}

// ============================================================================
extern "C" void kernel_launch(void* const* d_in, const int* in_sizes, int n_in,
                              void* d_out, int out_size, void* d_ws,
                              size_t ws_size, hipStream_t stream) {
  const float* feats[5];
  for (int i = 0; i < 5; ++i) feats[i] = (const float*)d_in[i];
  const float* reg_w0 = (const float*)d_in[5];
  const float* reg_b0 = (const float*)d_in[6];
  const float* reg_w1 = (const float*)d_in[7];
  const float* reg_b1 = (const float*)d_in[8];
  const float* cls_w0 = (const float*)d_in[9];
  const float* cls_b0 = (const float*)d_in[10];
  const float* cls_w1 = (const float*)d_in[11];
  const float* cls_b1 = (const float*)d_in[12];
  const float* reg_head_w = (const float*)d_in[13];
  const float* reg_head_b = (const float*)d_in[14];
  const float* cls_head_w = (const float*)d_in[15];
  const float* cls_head_b = (const float*)d_in[16];
  const float* conf_w = (const float*)d_in[17];
  const float* conf_b = (const float*)d_in[18];

  unsigned short* ws = (unsigned short*)d_ws;
  static const size_t xoff[5] = {0ull, 33554432ull, 41943040ull, 44040192ull,
                                 44564480ull};
  unsigned short* t1 = ws + 44695552ull;
  unsigned short* t2 = ws + 78249984ull;
  unsigned short* wt4 = ws + 111804416ull;
  unsigned short* wh = ws + 114163712ull;
  unsigned short* wc = ws + 114171904ull;
  unsigned short* zp = ws + 114188288ull;
  float* hbuf_all = (float*)((char*)d_ws + 228376704ull);

  prep_convw<<<9216, 256, 0, stream>>>(reg_w0, reg_w1, cls_w0, cls_w1, wt4);
  prep_small<<<97, 256, 0, stream>>>(cls_head_w, reg_head_w, conf_w, wc, wh,
                                     zp);

  static const int logWs[5] = {7, 6, 5, 4, 3};
  static const int lvl_off[5] = {0, 65536, 81920, 86016, 87040};
  static const int m_off[5] = {0, 131072, 163840, 172032, 174080};
  static const float strd[5] = {8.f, 16.f, 32.f, 64.f, 128.f};

  for (int l = 0; l < 5; ++l) {
    int HW = 1 << (2 * logWs[l]);
    to_nhwc<<<dim3(HW / 64, 8), 256, 0, stream>>>(feats[l], ws + xoff[l], HW,
                                                  2 * logWs[l]);
  }

  float* scores = (float*)d_out;
  float* boxes = (float*)d_out + SCORES_TOTAL;

  for (int l = 0; l < 5; ++l) {
    const int logW = logWs[l];
    const int HW = 1 << (2 * logW);
    const int M = 8 * HW;
    float* hb = hbuf_all + (size_t)m_off[l] * 24;
    dim3 cgrid(M / 128, 2);
    conv3x3_mfma<<<cgrid, 256, 0, stream>>>(ws + xoff[l], wt4 + 0ull * 589824,
                                            reg_b0, zp, t1, logW);
    conv3x3_mfma<<<cgrid, 256, 0, stream>>>(t1, wt4 + 1ull * 589824, reg_b1,
                                            zp, t2, logW);
    head24_mfma<<<M / 256, 256, 0, stream>>>(t2, wh, reg_head_b, conf_b, hb);
    conv3x3_mfma<<<cgrid, 256, 0, stream>>>(ws + xoff[l], wt4 + 2ull * 589824,
                                            cls_b0, zp, t1, logW);
    conv3x3_mfma<<<cgrid, 256, 0, stream>>>(t1, wt4 + 3ull * 589824, cls_b1,
                                            zp, t2, logW);
    cls_scores<<<M / 256, 256, 0, stream>>>(t2, wc, cls_head_b, hb, scores,
                                            2 * logW, lvl_off[l]);
    decode_k<<<(M * 4 + 255) / 256, 256, 0, stream>>>(
        hb, boxes, 2 * logW, logW, lvl_off[l], strd[l], M * 4);
  }
}

// Round 5
// 1828.527 us; speedup vs baseline: 1.4695x; 1.0172x over previous
//
#include <hip/hip_runtime.h>

// ============================================================================
// RetinaNetHead (S2ANet-style rotated head), MI355X gfx950.
// R5: cut LDS-read:MFMA ratio (R4 was LDS+bank-conflict bound):
//   - conv1 of both towers FUSED (shared A tile, two B tiles, two acc banks)
//   - conv2 widened to 128Mx256N blocks (wave tile 64x128)
//   Both: 12 ds_read_b128 per 64 MFMA (R4: 8 per 32).
// Staging via global_load_lds(16B) with zero-page clamp for conv halo.
// fp32 accum; logits/decode fp32.
//
// Workspace (ushort units):
//   [0)            feats NHWC fp16 (5 levels; region reused as conv2 output)
//   [44,695,552)   t1r fp16 (reg-tower conv1 out)
//   [78,249,984)   t1c fp16 (cls-tower conv1 out)
//   [111,804,416)  conv weights fp16 4x[9][256][256]
//   [114,163,712)  wh fp16 [32][256]
//   [114,171,904)  wc fp16 [64][256]
//   [114,188,288)  zp (64 ushorts of zeros; 16B zero page)
//   byte 228,376,704: hbuf fp32 [174592][24]   (total ~245.14 MB)
// ============================================================================

typedef __attribute__((ext_vector_type(8))) _Float16 f16x8;
typedef __attribute__((ext_vector_type(4))) float f32x4;

#define SCORES_TOTAL 10475520ull  // 8*87296*15

__device__ __forceinline__ unsigned short f2h(float f) {
  union { _Float16 h; unsigned short u; } x;
  x.h = (_Float16)f;
  return x.u;
}

__device__ __forceinline__ float sigmf(float x) {
  return 1.0f / (1.0f + expf(-x));
}

__device__ __forceinline__ void gload_lds16(const unsigned short* g,
                                            unsigned short* l) {
  __builtin_amdgcn_global_load_lds(
      (const __attribute__((address_space(1))) unsigned int*)g,
      (__attribute__((address_space(3))) unsigned int*)l, 16, 0, 0);
}

// ---------------------------------------------------------------- weight prep
__global__ __launch_bounds__(256) void prep_convw(
    const float* __restrict__ w0, const float* __restrict__ w1,
    const float* __restrict__ w2, const float* __restrict__ w3,
    unsigned short* __restrict__ wtout) {
  int g = blockIdx.x * 256 + threadIdx.x;  // < 4*589824 = 2359296
  int q = g >> 16;            // 0..35
  int wsel = q / 9;
  int kk = q - wsel * 9;      // ky*3+kx
  int r = g & 65535;
  int oc = r >> 8, ic = r & 255;
  const float* src = (wsel == 0) ? w0 : (wsel == 1) ? w1 : (wsel == 2) ? w2 : w3;
  float v = src[(size_t)(oc * 256 + ic) * 9 + kk];  // OIHW flat
  wtout[(size_t)wsel * 589824 + (size_t)((kk << 8) + oc) * 256 + ic] = f2h(v);
}

// wc [64][256], wh [32][256], zero page
__global__ __launch_bounds__(256) void prep_small(
    const float* __restrict__ clsh, const float* __restrict__ regh,
    const float* __restrict__ confw,
    unsigned short* __restrict__ wc, unsigned short* __restrict__ wh,
    unsigned short* __restrict__ zp) {
  int g = blockIdx.x * 256 + threadIdx.x;
  if (g < 16384) {
    int row = g >> 8, ic = g & 255;
    float v = (row < 60) ? clsh[row * 256 + ic] : 0.0f;
    wc[g] = f2h(v);
  } else if (g < 24576) {
    int gg = g - 16384;
    int row = gg >> 8, ic = gg & 255;
    float v = 0.0f;
    if (row < 20) v = regh[row * 256 + ic];
    else if (row < 24) v = confw[(row - 20) * 256 + ic];
    wh[gg] = f2h(v);
  } else if (g < 24640) {
    zp[g - 24576] = 0;
  }
}

// ---------------------------------------------------- NCHW fp32 -> NHWC fp16
__global__ __launch_bounds__(256) void to_nhwc(
    const float* __restrict__ in, unsigned short* __restrict__ out,
    int HW, int logHW) {
  __shared__ unsigned short L[64][258];
  const int t = threadIdx.x;
  const int b = blockIdx.y;
  const int hw0 = blockIdx.x * 64;
#pragma unroll
  for (int it = 0; it < 16; ++it) {
    int c = it * 16 + (t >> 4);
    int j4 = (t & 15) * 4;
    float4 v = *reinterpret_cast<const float4*>(
        in + (size_t)(b * 256 + c) * HW + hw0 + j4);
    L[j4 + 0][c] = f2h(v.x);
    L[j4 + 1][c] = f2h(v.y);
    L[j4 + 2][c] = f2h(v.z);
    L[j4 + 3][c] = f2h(v.w);
  }
  __syncthreads();
#pragma unroll
  for (int it = 0; it < 16; ++it) {
    int j = it * 4 + (t >> 6);
    int c4 = (t & 63) * 4;
    unsigned v0 = (unsigned)L[j][c4 + 0] | ((unsigned)L[j][c4 + 1] << 16);
    unsigned v1 = (unsigned)L[j][c4 + 2] | ((unsigned)L[j][c4 + 3] << 16);
    uint2 v = make_uint2(v0, v1);
    *reinterpret_cast<uint2*>(
        out + ((size_t)(b << logHW) + hw0 + j) * 256 + c4) = v;
  }
}

// --------------------------- conv1 both towers fused: 128Mx128N, 2 acc banks
__global__ __launch_bounds__(256, 2) void conv3x3_fused2(
    const unsigned short* __restrict__ xin,   // [M][256] NHWC fp16
    const unsigned short* __restrict__ wtR,   // [9][256][256] fp16 (reg)
    const unsigned short* __restrict__ wtC,   // [9][256][256] fp16 (cls)
    const float* __restrict__ biasR, const float* __restrict__ biasC,
    const unsigned short* __restrict__ zp,
    unsigned short* __restrict__ outR, unsigned short* __restrict__ outC,
    int logW) {
  const int logHW = 2 * logW;
  const int H = 1 << logW, W = H;
  __shared__ unsigned short Al[128 * 64];
  __shared__ unsigned short BlR[128 * 64];
  __shared__ unsigned short BlC[128 * 64];

  const int t = threadIdx.x;
  const int lane = t & 63;
  const int wv = t >> 6;
  const int wm = wv >> 1, wn = wv & 1;
  const int m0 = blockIdx.x * 128, n0 = blockIdx.y * 128;

  const int rsl = lane >> 3;
  const int chk = lane & 7;

  int hS[4], wS[4];
  const unsigned short* aptr[4];
  const unsigned short* bptrR[4];
  const unsigned short* bptrC[4];
  unsigned short* aldst[4];
  unsigned short* bldstR[4];
  unsigned short* bldstC[4];
#pragma unroll
  for (int i = 0; i < 4; ++i) {
    int slot = (wv << 2) + i;
    int m = m0 + (slot << 3) + rsl;
    int hw = m & ((1 << logHW) - 1);
    hS[i] = hw >> logW;
    wS[i] = hw & (W - 1);
    aptr[i] = xin + ((size_t)m << 8) + (chk << 3);
    int brow = n0 + (slot << 3) + rsl;
    bptrR[i] = wtR + ((size_t)brow << 8) + (chk << 3);
    bptrC[i] = wtC + ((size_t)brow << 8) + (chk << 3);
    aldst[i] = Al + (slot << 9);
    bldstR[i] = BlR + (slot << 9);
    bldstC[i] = BlC + (slot << 9);
  }

  f32x4 accR[4][4], accC[4][4];
#pragma unroll
  for (int i = 0; i < 4; ++i)
#pragma unroll
    for (int j = 0; j < 4; ++j) {
      accR[i][j] = (f32x4){0.f, 0.f, 0.f, 0.f};
      accC[i][j] = (f32x4){0.f, 0.f, 0.f, 0.f};
    }

  const int arow = (wm << 6) + (lane & 15);
  const int brow = (wn << 6) + (lane & 15);
  const int kb = ((lane >> 4) << 4);

#pragma unroll 1
  for (int kk = 0; kk < 9; ++kk) {
    const int dy = kk / 3 - 1, dx = kk - (kk / 3) * 3 - 1;
    const int moff = (dy * W + dx) << 8;
    bool va[4];
#pragma unroll
    for (int i = 0; i < 4; ++i)
      va[i] = ((unsigned)(hS[i] + dy) < (unsigned)H) &
              ((unsigned)(wS[i] + dx) < (unsigned)W);
    const size_t bko = (size_t)kk << 16;
#pragma unroll 1
    for (int icq = 0; icq < 4; ++icq) {
      const int ic0 = icq << 6;
      __syncthreads();
#pragma unroll
      for (int i = 0; i < 4; ++i) {
        const unsigned short* g = va[i] ? (aptr[i] + moff + ic0) : zp;
        gload_lds16(g, aldst[i]);
      }
#pragma unroll
      for (int i = 0; i < 4; ++i) gload_lds16(bptrR[i] + bko + ic0, bldstR[i]);
#pragma unroll
      for (int i = 0; i < 4; ++i) gload_lds16(bptrC[i] + bko + ic0, bldstC[i]);
      __syncthreads();
#pragma unroll
      for (int ks = 0; ks < 2; ++ks) {
        f16x8 a[4], bR[4], bC[4];
#pragma unroll
        for (int mf = 0; mf < 4; ++mf)
          a[mf] = *reinterpret_cast<const f16x8*>(
              (const char*)Al + ((arow + (mf << 4)) << 7) + kb + (ks << 6));
#pragma unroll
        for (int nf = 0; nf < 4; ++nf) {
          bR[nf] = *reinterpret_cast<const f16x8*>(
              (const char*)BlR + ((brow + (nf << 4)) << 7) + kb + (ks << 6));
          bC[nf] = *reinterpret_cast<const f16x8*>(
              (const char*)BlC + ((brow + (nf << 4)) << 7) + kb + (ks << 6));
        }
#pragma unroll
        for (int mf = 0; mf < 4; ++mf)
#pragma unroll
          for (int nf = 0; nf < 4; ++nf) {
            accR[mf][nf] = __builtin_amdgcn_mfma_f32_16x16x32_f16(
                a[mf], bR[nf], accR[mf][nf], 0, 0, 0);
            accC[mf][nf] = __builtin_amdgcn_mfma_f32_16x16x32_f16(
                a[mf], bC[nf], accC[mf][nf], 0, 0, 0);
          }
      }
    }
  }

  const int mrow0 = m0 + (wm << 6) + ((lane >> 4) << 2);
  const int ocol0 = n0 + (wn << 6) + (lane & 15);
#pragma unroll
  for (int nf = 0; nf < 4; ++nf) {
    int oc = ocol0 + (nf << 4);
    float biR = biasR[oc], biC = biasC[oc];
#pragma unroll
    for (int mf = 0; mf < 4; ++mf)
#pragma unroll
      for (int r = 0; r < 4; ++r) {
        int m = mrow0 + (mf << 4) + r;
        outR[((size_t)m << 8) + oc] = f2h(fmaxf(accR[mf][nf][r] + biR, 0.0f));
        outC[((size_t)m << 8) + oc] = f2h(fmaxf(accC[mf][nf][r] + biC, 0.0f));
      }
  }
}

// ----------------------------- conv2: 128Mx256N block, wave tile 64x128
__global__ __launch_bounds__(256, 2) void conv3x3_wide(
    const unsigned short* __restrict__ xin,  // [M][256] NHWC fp16
    const unsigned short* __restrict__ wt,   // [9][256][256] fp16
    const float* __restrict__ bias,          // [256]
    const unsigned short* __restrict__ zp,
    unsigned short* __restrict__ yout,       // [M][256] NHWC fp16
    int logW) {
  const int logHW = 2 * logW;
  const int H = 1 << logW, W = H;
  __shared__ unsigned short Al[128 * 64];   // 16KB
  __shared__ unsigned short Bl[256 * 64];   // 32KB

  const int t = threadIdx.x;
  const int lane = t & 63;
  const int wv = t >> 6;
  const int wm = wv >> 1, wn = wv & 1;  // wave tile: 64M x 128N
  const int m0 = blockIdx.x * 128;

  const int rsl = lane >> 3;
  const int chk = lane & 7;

  int hS[4], wS[4];
  const unsigned short* aptr[4];
  unsigned short* aldst[4];
#pragma unroll
  for (int i = 0; i < 4; ++i) {
    int slot = (wv << 2) + i;
    int m = m0 + (slot << 3) + rsl;
    int hw = m & ((1 << logHW) - 1);
    hS[i] = hw >> logW;
    wS[i] = hw & (W - 1);
    aptr[i] = xin + ((size_t)m << 8) + (chk << 3);
    aldst[i] = Al + (slot << 9);
  }
  const unsigned short* bptr[8];
  unsigned short* bldst[8];
#pragma unroll
  for (int i = 0; i < 8; ++i) {
    int slot = (wv << 3) + i;       // 0..31
    int row = (slot << 3) + rsl;    // 0..255
    bptr[i] = wt + ((size_t)row << 8) + (chk << 3);
    bldst[i] = Bl + (slot << 9);
  }

  f32x4 acc[4][8];
#pragma unroll
  for (int i = 0; i < 4; ++i)
#pragma unroll
    for (int j = 0; j < 8; ++j) acc[i][j] = (f32x4){0.f, 0.f, 0.f, 0.f};

  const int arow = (wm << 6) + (lane & 15);
  const int brow = (wn << 7) + (lane & 15);
  const int kb = ((lane >> 4) << 4);

#pragma unroll 1
  for (int kk = 0; kk < 9; ++kk) {
    const int dy = kk / 3 - 1, dx = kk - (kk / 3) * 3 - 1;
    const int moff = (dy * W + dx) << 8;
    bool va[4];
#pragma unroll
    for (int i = 0; i < 4; ++i)
      va[i] = ((unsigned)(hS[i] + dy) < (unsigned)H) &
              ((unsigned)(wS[i] + dx) < (unsigned)W);
    const size_t bko = (size_t)kk << 16;
#pragma unroll 1
    for (int icq = 0; icq < 4; ++icq) {
      const int ic0 = icq << 6;
      __syncthreads();
#pragma unroll
      for (int i = 0; i < 4; ++i) {
        const unsigned short* g = va[i] ? (aptr[i] + moff + ic0) : zp;
        gload_lds16(g, aldst[i]);
      }
#pragma unroll
      for (int i = 0; i < 8; ++i) gload_lds16(bptr[i] + bko + ic0, bldst[i]);
      __syncthreads();
#pragma unroll
      for (int ks = 0; ks < 2; ++ks) {
        f16x8 a[4], b[8];
#pragma unroll
        for (int mf = 0; mf < 4; ++mf)
          a[mf] = *reinterpret_cast<const f16x8*>(
              (const char*)Al + ((arow + (mf << 4)) << 7) + kb + (ks << 6));
#pragma unroll
        for (int nf = 0; nf < 8; ++nf)
          b[nf] = *reinterpret_cast<const f16x8*>(
              (const char*)Bl + ((brow + (nf << 4)) << 7) + kb + (ks << 6));
#pragma unroll
        for (int mf = 0; mf < 4; ++mf)
#pragma unroll
          for (int nf = 0; nf < 8; ++nf)
            acc[mf][nf] = __builtin_amdgcn_mfma_f32_16x16x32_f16(
                a[mf], b[nf], acc[mf][nf], 0, 0, 0);
      }
    }
  }

  const int mrow0 = m0 + (wm << 6) + ((lane >> 4) << 2);
  const int ocol0 = (wn << 7) + (lane & 15);
#pragma unroll
  for (int nf = 0; nf < 8; ++nf) {
    int oc = ocol0 + (nf << 4);
    float bi = bias[oc];
#pragma unroll
    for (int mf = 0; mf < 4; ++mf)
#pragma unroll
      for (int r = 0; r < 4; ++r) {
        int m = mrow0 + (mf << 4) + r;
        yout[((size_t)m << 8) + oc] = f2h(fmaxf(acc[mf][nf][r] + bi, 0.0f));
      }
  }
}

// -------------------------------------------- bbox(20)+conf(4) head -> hbuf
__global__ __launch_bounds__(256) void head24_mfma(
    const unsigned short* __restrict__ t2,  // [M][256] fp16
    const unsigned short* __restrict__ wh,  // [32][256] fp16 (24 valid)
    const float* __restrict__ regb, const float* __restrict__ confb,
    float* __restrict__ hbuf) {             // [M][24] fp32
  const int t = threadIdx.x, lane = t & 63, wv = t >> 6;
  const int rowb = blockIdx.x * 256 + wv * 64;
  const int kgrp = (lane >> 4) << 3;
  const int l15 = lane & 15;
  f32x4 acc[4][2];
#pragma unroll
  for (int i = 0; i < 4; ++i)
#pragma unroll
    for (int j = 0; j < 2; ++j) acc[i][j] = (f32x4){0.f, 0.f, 0.f, 0.f};
#pragma unroll
  for (int k0 = 0; k0 < 256; k0 += 32) {
    f16x8 a[4], b[2];
#pragma unroll
    for (int mf = 0; mf < 4; ++mf)
      a[mf] = *reinterpret_cast<const f16x8*>(
          t2 + (((size_t)(rowb + (mf << 4) + l15)) << 8) + k0 + kgrp);
#pragma unroll
    for (int nf = 0; nf < 2; ++nf)
      b[nf] = *reinterpret_cast<const f16x8*>(
          wh + (size_t)(((nf << 4) + l15) << 8) + k0 + kgrp);
#pragma unroll
    for (int mf = 0; mf < 4; ++mf)
#pragma unroll
      for (int nf = 0; nf < 2; ++nf)
        acc[mf][nf] = __builtin_amdgcn_mfma_f32_16x16x32_f16(
            a[mf], b[nf], acc[mf][nf], 0, 0, 0);
  }
#pragma unroll
  for (int nf = 0; nf < 2; ++nf) {
    int c = (nf << 4) + l15;
    if (c < 24) {
      float bi = (c < 20) ? regb[c] : confb[c - 20];
#pragma unroll
      for (int mf = 0; mf < 4; ++mf)
#pragma unroll
        for (int r = 0; r < 4; ++r) {
          int m = rowb + (mf << 4) + ((lane >> 4) << 2) + r;
          hbuf[(size_t)m * 24 + c] = acc[mf][nf][r] + bi;
        }
    }
  }
}

// ------------------------------------------- cls head + sigmoid*sigmoid out
__global__ __launch_bounds__(256) void cls_scores(
    const unsigned short* __restrict__ t2,  // [M][256] fp16
    const unsigned short* __restrict__ wc,  // [64][256] fp16 (60 valid)
    const float* __restrict__ clsb,
    const float* __restrict__ hbuf,         // [M][24] fp32 (conf at 20..23)
    float* __restrict__ outs,               // d_out scores base
    int logHW, int lvl_off) {
  const int t = threadIdx.x, lane = t & 63, wv = t >> 6;
  const int rowb = blockIdx.x * 256 + wv * 64;
  const int kgrp = (lane >> 4) << 3;
  const int l15 = lane & 15;
  const int HWm1 = (1 << logHW) - 1;
  f32x4 acc[4][4];
#pragma unroll
  for (int i = 0; i < 4; ++i)
#pragma unroll
    for (int j = 0; j < 4; ++j) acc[i][j] = (f32x4){0.f, 0.f, 0.f, 0.f};
#pragma unroll
  for (int k0 = 0; k0 < 256; k0 += 32) {
    f16x8 a[4], b[4];
#pragma unroll
    for (int mf = 0; mf < 4; ++mf)
      a[mf] = *reinterpret_cast<const f16x8*>(
          t2 + (((size_t)(rowb + (mf << 4) + l15)) << 8) + k0 + kgrp);
#pragma unroll
    for (int nf = 0; nf < 4; ++nf)
      b[nf] = *reinterpret_cast<const f16x8*>(
          wc + (size_t)(((nf << 4) + l15) << 8) + k0 + kgrp);
#pragma unroll
    for (int mf = 0; mf < 4; ++mf)
#pragma unroll
      for (int nf = 0; nf < 4; ++nf)
        acc[mf][nf] = __builtin_amdgcn_mfma_f32_16x16x32_f16(
            a[mf], b[nf], acc[mf][nf], 0, 0, 0);
  }
#pragma unroll
  for (int nf = 0; nf < 4; ++nf) {
    int c = (nf << 4) + l15;
    if (c < 60) {
      int ai = c / 15, ci = c - ai * 15;
      float bi = clsb[c];
#pragma unroll
      for (int mf = 0; mf < 4; ++mf)
#pragma unroll
        for (int r = 0; r < 4; ++r) {
          int m = rowb + (mf << 4) + ((lane >> 4) << 2) + r;
          float logit = acc[mf][nf][r] + bi;
          float conf = hbuf[(size_t)m * 24 + 20 + ai];
          float sc = sigmf(logit) * sigmf(conf);
          int b = m >> logHW;
          int hw = m & HWm1;
          int loc = lvl_off + (hw << 2) + ai;
          outs[(size_t)b * 1309440 + (size_t)loc * 15 + ci] = sc;
        }
    }
  }
}

// ------------------------------------------------------------- rbox decode
__global__ __launch_bounds__(256) void decode_k(
    const float* __restrict__ hbuf, float* __restrict__ outb,
    int logHW, int logW, int lvl_off, float stride, int total) {
  int tid = blockIdx.x * 256 + threadIdx.x;
  if (tid >= total) return;
  int m = tid >> 2, a = tid & 3;
  const float ANG[4] = {-0.39269908169872414f, 0.39269908169872414f,
                        1.1780972450961724f, 1.9634954084936207f};
  const float* d = hbuf + (size_t)m * 24 + a * 5;
  float dx = d[0], dy = d[1], dw = d[2], dh = d[3], da = d[4];
  int b = m >> logHW, hw = m & ((1 << logHW) - 1);
  int h = hw >> logW, w = hw & ((1 << logW) - 1);
  float ctr = 0.5f * (stride - 1.0f);
  float rx = w * stride + ctr, ry = h * stride + ctr;
  float rw = stride * 1.6329931618554521f;  // 4/sqrt(6)
  float rh = stride * 9.7979589711327124f;  // 4*sqrt(6)
  const float MR = 13.815510557964274f;     // |log(1e-6)|
  dw = fminf(fmaxf(dw, -MR), MR);
  dh = fminf(fmaxf(dh, -MR), MR);
  float gx = dx * rw + rx;
  float gy = dy * rh + ry;
  float gw = rw * expf(dw);
  float gh = rh * expf(dh);
  float v = da + ANG[a] + 0.7853981633974483f;
  float r = fmodf(v, 3.14159265358979323846f);
  if (r < 0.0f) r += 3.14159265358979323846f;
  float ga = r - 0.7853981633974483f;
  int loc = lvl_off + (hw << 2) + a;
  size_t base = (size_t)b * 436480 + (size_t)loc * 5;
  outb[base + 0] = gx;
  outb[base + 1] = gy;
  outb[base + 2] = gw;
  outb[base + 3] = gh;
  outb[base + 4] = ga;
}

// ============================================================================
extern "C" void kernel_launch(void* const* d_in, const int* in_sizes, int n_in,
                              void* d_out, int out_size, void* d_ws,
                              size_t ws_size, hipStream_t stream) {
  const float* feats[5];
  for (int i = 0; i < 5; ++i) feats[i] = (const float*)d_in[i];
  const float* reg_w0 = (const float*)d_in[5];
  const float* reg_b0 = (const float*)d_in[6];
  const float* reg_w1 = (const float*)d_in[7];
  const float* reg_b1 = (const float*)d_in[8];
  const float* cls_w0 = (const float*)d_in[9];
  const float* cls_b0 = (const float*)d_in[10];
  const float* cls_w1 = (const float*)d_in[11];
  const float* cls_b1 = (const float*)d_in[12];
  const float* reg_head_w = (const float*)d_in[13];
  const float* reg_head_b = (const float*)d_in[14];
  const float* cls_head_w = (const float*)d_in[15];
  const float* cls_head_b = (const float*)d_in[16];
  const float* conf_w = (const float*)d_in[17];
  const float* conf_b = (const float*)d_in[18];

  unsigned short* ws = (unsigned short*)d_ws;
  static const size_t xoff[5] = {0ull, 33554432ull, 41943040ull, 44040192ull,
                                 44564480ull};
  unsigned short* t1r = ws + 44695552ull;
  unsigned short* t1c = ws + 78249984ull;
  unsigned short* wt4 = ws + 111804416ull;
  unsigned short* wh = ws + 114163712ull;
  unsigned short* wc = ws + 114171904ull;
  unsigned short* zp = ws + 114188288ull;
  float* hbuf_all = (float*)((char*)d_ws + 228376704ull);

  prep_convw<<<9216, 256, 0, stream>>>(reg_w0, reg_w1, cls_w0, cls_w1, wt4);
  prep_small<<<97, 256, 0, stream>>>(cls_head_w, reg_head_w, conf_w, wc, wh,
                                     zp);

  static const int logWs[5] = {7, 6, 5, 4, 3};
  static const int lvl_off[5] = {0, 65536, 81920, 86016, 87040};
  static const int m_off[5] = {0, 131072, 163840, 172032, 174080};
  static const float strd[5] = {8.f, 16.f, 32.f, 64.f, 128.f};

  for (int l = 0; l < 5; ++l) {
    int HW = 1 << (2 * logWs[l]);
    to_nhwc<<<dim3(HW / 64, 8), 256, 0, stream>>>(feats[l], ws + xoff[l], HW,
                                                  2 * logWs[l]);
  }

  float* scores = (float*)d_out;
  float* boxes = (float*)d_out + SCORES_TOTAL;

  for (int l = 0; l < 5; ++l) {
    const int logW = logWs[l];
    const int HW = 1 << (2 * logW);
    const int M = 8 * HW;
    float* hb = hbuf_all + (size_t)m_off[l] * 24;
    unsigned short* x = ws + xoff[l];    // NHWC input; dead after conv1 -> t2
    unsigned short* t2 = x;              // conv2 output reuses x region

    conv3x3_fused2<<<dim3(M / 128, 2), 256, 0, stream>>>(
        x, wt4 + 0ull * 589824, wt4 + 2ull * 589824, reg_b0, cls_b0, zp, t1r,
        t1c, logW);
    conv3x3_wide<<<M / 128, 256, 0, stream>>>(t1r, wt4 + 1ull * 589824,
                                              reg_b1, zp, t2, logW);
    head24_mfma<<<M / 256, 256, 0, stream>>>(t2, wh, reg_head_b, conf_b, hb);
    conv3x3_wide<<<M / 128, 256, 0, stream>>>(t1c, wt4 + 3ull * 589824,
                                              cls_b1, zp, t2, logW);
    cls_scores<<<M / 256, 256, 0, stream>>>(t2, wc, cls_head_b, hb, scores,
                                            2 * logW, lvl_off[l]);
    decode_k<<<(M * 4 + 255) / 256, 256, 0, stream>>>(
        hb, boxes, 2 * logW, logW, lvl_off[l], strd[l], M * 4);
  }
}